// Round 2
// baseline (2629.829 us; speedup 1.0000x reference)
//
#include <hip/hip_runtime.h>
#include <hip/hip_bf16.h>
#include <math.h>

// Problem constants
#define N_   16
#define CI_  64
#define CO_  128
#define HW_  3136       // 56*56
#define W56  56
#define MU_  0.1f
#define THR_ 0.01f      // MU * LAMBDA

// ---------------------------------------------------------------------------
// Weight normalization: Wn[co][i] = W[co][i] / sqrt(sum_i W^2 + 1e-12)
// 128 blocks (one per output filter) x 64 threads (one wave).
// ---------------------------------------------------------------------------
__global__ __launch_bounds__(64) void wnorm_kernel(
    const float* __restrict__ Wsrc, float* __restrict__ Wn) {
    int co = blockIdx.x;
    int lane = threadIdx.x;
    const float* wp = Wsrc + co * 576;
    float vals[9];
    float s = 0.f;
#pragma unroll
    for (int k = 0; k < 9; ++k) {
        float v = wp[lane + 64 * k];
        vals[k] = v;
        s += v * v;
    }
#pragma unroll
    for (int off = 32; off; off >>= 1) s += __shfl_xor(s, off, 64);
    float inv = 1.0f / sqrtf(s + 1e-12f);
#pragma unroll
    for (int k = 0; k < 9; ++k) Wn[co * 576 + lane + 64 * k] = vals[k] * inv;
}

// ---------------------------------------------------------------------------
// Forward conv 64->128 (pad 1, stride 1) with fused FISTA epilogue.
// grid = (13 pixel-chunks, 32 co-groups of 4, 16 n), block = 256.
// mode 0: c = relu(MU*acc - thr); y = c; cp = c          (iteration 0)
// mode 1: c = relu(y + MU*acc - thr); y = c + beta*(c - cp); cp = c;
//         optionally write c to fp32 out (final iteration)
// ---------------------------------------------------------------------------
__global__ __launch_bounds__(256) void conv_fwd_kernel(
    const float* __restrict__ in,    // [N,64,HW]
    const float* __restrict__ Wn,    // [128,576] row-major [co][ci*9+k]
    float* __restrict__ y,           // [N,128,HW]
    float* __restrict__ cp,          // [N,128,HW]
    float* __restrict__ outp,        // nullable
    int mode, float beta) {
    __shared__ float sh[4 * 576];
    const int tid = threadIdx.x;
    const int cg = blockIdx.y;   // group of 4 output channels
    const int n  = blockIdx.z;
    const float* wsrc = Wn + cg * 2304;   // 4 contiguous co rows
    for (int i = tid; i < 2304; i += 256) sh[i] = wsrc[i];
    __syncthreads();

    const int p = blockIdx.x * 256 + tid;
    if (p >= HW_) return;
    const int h = p / W56, w = p - h * W56;

    int off[9];
    bool val[9];
#pragma unroll
    for (int t = 0; t < 9; ++t) {
        int dh = t / 3 - 1, dw = t % 3 - 1;
        int hh = h + dh, ww = w + dw;
        val[t] = ((unsigned)hh < 56u) && ((unsigned)ww < 56u);
        off[t] = hh * W56 + ww;
    }

    float acc0 = 0.f, acc1 = 0.f, acc2 = 0.f, acc3 = 0.f;
    const float* xb = in + (size_t)n * CI_ * HW_;
    for (int ci = 0; ci < CI_; ++ci) {
        const float* xp = xb + ci * HW_;
        float v[9];
#pragma unroll
        for (int t = 0; t < 9; ++t) v[t] = val[t] ? xp[off[t]] : 0.f;
        const float* w0 = sh + ci * 9;
#pragma unroll
        for (int t = 0; t < 9; ++t) {
            acc0 = fmaf(v[t], w0[t], acc0);
            acc1 = fmaf(v[t], w0[576 + t], acc1);
            acc2 = fmaf(v[t], w0[1152 + t], acc2);
            acc3 = fmaf(v[t], w0[1728 + t], acc3);
        }
    }

    float accs[4] = {acc0, acc1, acc2, acc3};
#pragma unroll
    for (int j = 0; j < 4; ++j) {
        size_t o = ((size_t)n * CO_ + cg * 4 + j) * HW_ + p;
        if (mode == 0) {
            float c = fmaxf(MU_ * accs[j] - THR_, 0.f);
            y[o] = c;
            cp[o] = c;
        } else {
            float c = fmaxf(y[o] + MU_ * accs[j] - THR_, 0.f);
            float yn = c + beta * (c - cp[o]);
            y[o] = yn;
            cp[o] = c;
            if (outp) outp[o] = c;
        }
    }
}

// ---------------------------------------------------------------------------
// Transpose conv 128->64 (stride 1, effective pad 1) with fused residual:
// r[n,ci,h,w] = x[n,ci,h,w] - sum_{co,t} y[n,co,h+1-dh,w+1-dw] * Wn[co,ci,t]
// grid = (13 pixel-chunks, 16 ci-groups of 4, 16 n), block = 256.
// ---------------------------------------------------------------------------
__global__ __launch_bounds__(256) void conv_t_kernel(
    const float* __restrict__ y,     // [N,128,HW]
    const float* __restrict__ Wn,    // [128,576]
    const float* __restrict__ xf,    // [N,64,HW]
    float* __restrict__ r) {         // [N,64,HW]
    __shared__ float sh[4 * 1152];   // [j][co][9]
    const int tid = threadIdx.x;
    const int cig = blockIdx.y;      // group of 4 output (=ci) channels
    const int n = blockIdx.z;
    for (int i = tid; i < 4608; i += 256) {
        int j = i / 1152;
        int rem = i - j * 1152;
        int co = rem / 9;
        int k = rem - co * 9;
        sh[i] = Wn[co * 576 + (cig * 4 + j) * 9 + k];
    }
    __syncthreads();

    const int p = blockIdx.x * 256 + tid;
    if (p >= HW_) return;
    const int h = p / W56, w = p - h * W56;

    int off[9];
    bool val[9];
#pragma unroll
    for (int t = 0; t < 9; ++t) {
        int ddh = t / 3, ddw = t % 3;
        int hh = h + 1 - ddh, ww = w + 1 - ddw;
        val[t] = ((unsigned)hh < 56u) && ((unsigned)ww < 56u);
        off[t] = hh * W56 + ww;
    }

    float acc0 = 0.f, acc1 = 0.f, acc2 = 0.f, acc3 = 0.f;
    const float* yb = y + (size_t)n * CO_ * HW_;
    for (int co = 0; co < CO_; ++co) {
        const float* yp = yb + co * HW_;
        float v[9];
#pragma unroll
        for (int t = 0; t < 9; ++t) v[t] = val[t] ? yp[off[t]] : 0.f;
        const float* w0 = sh + co * 9;
#pragma unroll
        for (int t = 0; t < 9; ++t) {
            acc0 = fmaf(v[t], w0[t], acc0);
            acc1 = fmaf(v[t], w0[1152 + t], acc1);
            acc2 = fmaf(v[t], w0[2304 + t], acc2);
            acc3 = fmaf(v[t], w0[3456 + t], acc3);
        }
    }

    float accs[4] = {acc0, acc1, acc2, acc3};
#pragma unroll
    for (int j = 0; j < 4; ++j) {
        size_t o = ((size_t)n * CI_ + cig * 4 + j) * HW_ + p;
        r[o] = xf[o] - accs[j];
    }
}

// ---------------------------------------------------------------------------
extern "C" void kernel_launch(void* const* d_in, const int* in_sizes, int n_in,
                              void* d_out, int out_size, void* d_ws, size_t ws_size,
                              hipStream_t stream) {
    const float* x = (const float*)d_in[0];  // [16,64,56,56] fp32
    const float* W = (const float*)d_in[1];  // [128,64,3,3]  fp32
    float* out = (float*)d_out;              // [16,128,56,56] fp32

    // Workspace layout (fp32): Wn | y | cp | r  (~64.5 MB total)
    const size_t XN = (size_t)N_ * CI_ * HW_;   // 3,211,264
    const size_t YN = (size_t)N_ * CO_ * HW_;   // 6,422,528
    float* Wn = (float*)d_ws;
    float* y  = Wn + 128 * 576;
    float* cp = y + YN;
    float* r  = cp + YN;

    hipLaunchKernelGGL(wnorm_kernel, dim3(128), dim3(64), 0, stream, W, Wn);

    dim3 gf(13, 32, 16), gt(13, 16, 16), b(256, 1, 1);

    // FISTA iteration 0: c = shrink(MU * conv(x, Wn)); y = c; c_prev = c
    hipLaunchKernelGGL(conv_fwd_kernel, gf, b, 0, stream,
                       x, Wn, y, cp, (float*)nullptr, 0, 0.f);

    double t = 1.0;
    for (int it = 1; it <= 5; ++it) {
        // r = x - conv_t(y, Wn)
        hipLaunchKernelGGL(conv_t_kernel, gt, b, 0, stream, y, Wn, x, r);
        double tn = (1.0 + sqrt(1.0 + 4.0 * t * t)) / 2.0;
        float beta = (float)((t - 1.0) / tn);
        // c = shrink(y + MU*conv(r,Wn)); y = c + beta*(c - cp); cp = c
        hipLaunchKernelGGL(conv_fwd_kernel, gf, b, 0, stream,
                           r, Wn, y, cp, (it == 5) ? out : (float*)nullptr,
                           1, beta);
        t = tn;
    }
}

// Round 4
// 444.832 us; speedup vs baseline: 5.9120x; 5.9120x over previous
//
#include <hip/hip_runtime.h>
#include <hip/hip_bf16.h>
#include <math.h>

typedef __attribute__((ext_vector_type(8))) short short8;
typedef __attribute__((ext_vector_type(16))) float f32x16;

#define MU_  0.1f
#define THR_ 0.01f

static __device__ inline short f2bf(float f) {
    __hip_bfloat16 h = __float2bfloat16(f);
    return *reinterpret_cast<short*>(&h);
}

// ---------------------------------------------------------------------------
// Zero a float4-aligned span (used for Rp+Yp pad init; harness poisons ws).
// ---------------------------------------------------------------------------
__global__ __launch_bounds__(256) void zero_kernel(float4* p, int n4) {
    int i = blockIdx.x * 256 + threadIdx.x;
    if (i < n4) p[i] = make_float4(0.f, 0.f, 0.f, 0.f);
}

// ---------------------------------------------------------------------------
// Normalize W and emit both GEMM-ready swizzled bf16 weight layouts.
// Wf[t][co][ci ^ ((co&7)<<3)] = Wn[co][ci*9+t]          (fwd A-operand)
// Wt[t][ci][co ^ ((ci&7)<<3)] = Wn[co][ci*9+(8-t)]      (conv_t A-operand)
// ---------------------------------------------------------------------------
__global__ __launch_bounds__(64) void wnorm_pack(
    const float* __restrict__ W, short* __restrict__ Wf, short* __restrict__ Wt) {
    int co = blockIdx.x, ci = threadIdx.x;
    const float* wp = W + (co * 64 + ci) * 9;
    float v[9]; float s = 0.f;
#pragma unroll
    for (int t = 0; t < 9; ++t) { v[t] = wp[t]; s += v[t] * v[t]; }
#pragma unroll
    for (int off = 32; off; off >>= 1) s += __shfl_xor(s, off, 64);
    float inv = 1.0f / sqrtf(s + 1e-12f);
#pragma unroll
    for (int t = 0; t < 9; ++t) {
        Wf[(t * 128 + co) * 64 + (ci ^ ((co & 7) << 3))] = f2bf(v[t] * inv);
        Wt[(t * 64 + ci) * 128 + (co ^ ((ci & 7) << 3))] = f2bf(v[8 - t] * inv);
    }
}

// ---------------------------------------------------------------------------
// Pack x (fp32 NCHW) -> Xp bf16 padded NHWC swizzled [n][58][68][64].
// Storage (row,s) <-> math (h=row-1, w=s-2); zeros elsewhere.
// ---------------------------------------------------------------------------
__global__ __launch_bounds__(256) void pack_x(
    const float* __restrict__ x, short* __restrict__ Xp) {
    __shared__ float lx[64 * 57];
    int row = blockIdx.x, n = blockIdx.y, tid = threadIdx.x;
    short* dst = Xp + ((size_t)(n * 58 + row) * 68) * 64;
    if (row >= 1 && row <= 56) {
        int h = row - 1;
        for (int j = tid; j < 64 * 56; j += 256) {
            int ci = j / 56, w = j - ci * 56;
            lx[ci * 57 + w] = x[((size_t)(n * 64 + ci)) * 3136 + h * 56 + w];
        }
        __syncthreads();
        for (int j = tid; j < 68 * 64; j += 256) {
            int s = j >> 6, ci = j & 63;
            float val = (s >= 2 && s < 58) ? lx[ci * 57 + (s - 2)] : 0.f;
            dst[(s << 6) + (ci ^ ((s & 7) << 3))] = f2bf(val);
        }
    } else {
        for (int j = tid; j < 68 * 64; j += 256) dst[j] = 0;
    }
}

// ---------------------------------------------------------------------------
// Forward conv 64->128 as implicit GEMM (M=co, K=t*64+ci, N=pixels) + fused
// FISTA epilogue. grid=(56 rows, 16 n), block=256 (4 waves of 32co x 64px).
// mode 0: it0; mode 1: middle iters; mode 2: final (write out only).
// ---------------------------------------------------------------------------
__global__ __launch_bounds__(256) void conv_fwd(
    const short* __restrict__ inp,   // [n][58][68][64] bf16 swz (Xp or Rp)
    const short* __restrict__ Wf,    // [9][128][64] bf16 swz
    float* __restrict__ y, float* __restrict__ cp,
    short* __restrict__ Yp,          // [n][58][68][128] bf16 swz
    float* __restrict__ outp, int mode, float beta) {
    __shared__ short xs[3 * 68 * 64];   // 26112 B; reused as transpose buf
    const int r = blockIdx.x + 1, n = blockIdx.y, tid = threadIdx.x;
    {   // stage 3 contiguous input rows
        const short8* src = (const short8*)(inp + ((size_t)(n * 58 + (r - 1)) * 68) * 64);
        short8* d = (short8*)xs;
        for (int j = tid; j < 13056 / 8; j += 256) d[j] = src[j];
    }
    __syncthreads();

    const int lane = tid & 63, wid = tid >> 6, qh = lane >> 5, v0 = lane & 31;
    const int co = wid * 32 + v0;
    int goffA[4], bg[3][4];
#pragma unroll
    for (int s = 0; s < 4; ++s) goffA[s] = 8 * ((2 * s + qh) ^ (co & 7));
#pragma unroll
    for (int dw = 0; dw < 3; ++dw) {
        int key = (v0 + dw + 1) & 7;
#pragma unroll
        for (int s = 0; s < 4; ++s) bg[dw][s] = 8 * ((2 * s + qh) ^ key);
    }
    const short* wbase = Wf + co * 64;

    f32x16 acc0, acc1;
#pragma unroll
    for (int i = 0; i < 16; ++i) { acc0[i] = 0.f; acc1[i] = 0.f; }

    short8 Af[2][4];
#pragma unroll
    for (int tt = 0; tt < 2; ++tt)
#pragma unroll
        for (int s = 0; s < 4; ++s)
            Af[tt][s] = *(const short8*)(wbase + tt * 8192 + goffA[s]);

#pragma unroll
    for (int t = 0; t < 9; ++t) {
        const int dh = t / 3, dw = t % 3;
        const int b_base = (dh * 68 + (v0 + dw + 1)) * 64;
#pragma unroll
        for (int s = 0; s < 4; ++s) {
            short8 b0v = *(const short8*)(xs + b_base + bg[dw][s]);
            short8 b1v = *(const short8*)(xs + b_base + 2048 + bg[dw][s]);
            acc0 = __builtin_amdgcn_mfma_f32_32x32x16_bf16(Af[t & 1][s], b0v, acc0, 0, 0, 0);
            acc1 = __builtin_amdgcn_mfma_f32_32x32x16_bf16(Af[t & 1][s], b1v, acc1, 0, 0, 0);
        }
        if (t + 2 < 9) {
#pragma unroll
            for (int s = 0; s < 4; ++s)
                Af[t & 1][s] = *(const short8*)(wbase + (t + 2) * 8192 + goffA[s]);
        }
    }

    // ---- epilogue ----
    __syncthreads();          // xs dead -> reuse as transpose buffer [64][136]
    short* tb = xs;
    const int h = r - 1;
#pragma unroll
    for (int tile = 0; tile < 2; ++tile) {
        const f32x16& acc = tile ? acc1 : acc0;
        const int v = tile * 32 + v0;
        const bool valid = v < 56;
        const size_t obase = ((size_t)n * 128) * 3136 + (size_t)h * 56 + v;
#pragma unroll
        for (int reg = 0; reg < 16; ++reg) {
            const int cr = wid * 32 + (reg & 3) + 8 * (reg >> 2) + 4 * qh;
            const size_t o = obase + (size_t)cr * 3136;
            const float a = acc[reg];
            float ynew = 0.f;
            if (mode == 0) {
                float c = fmaxf(MU_ * a - THR_, 0.f);
                ynew = c;
                if (valid) { y[o] = c; cp[o] = c; }
            } else if (mode == 1) {
                if (valid) {
                    float yo = y[o], cpo = cp[o];
                    float c = fmaxf(yo + MU_ * a - THR_, 0.f);
                    ynew = c + beta * (c - cpo);
                    y[o] = ynew; cp[o] = c;
                }
            } else {
                if (valid) {
                    float c = fmaxf(y[o] + MU_ * a - THR_, 0.f);
                    outp[o] = c;
                }
            }
            if (mode != 2) tb[v * 136 + cr] = f2bf(ynew);
        }
    }
    if (mode != 2) {
        __syncthreads();
        short* ydst = Yp + ((size_t)(n * 58 + r) * 68) * 128;
        for (int item = tid; item < 56 * 16; item += 256) {
            int v = item >> 4, g = item & 15;
            short8 val = *(const short8*)(tb + v * 136 + 8 * g);
            int s = v + 2;
            *(short8*)(ydst + s * 128 + 8 * (g ^ (s & 7))) = val;
        }
    }
}

// ---------------------------------------------------------------------------
// Transpose conv 128->64 as implicit GEMM (M=ci, K=t*128+co, N=pixels) with
// fused residual r = x - D^T y. grid=(56,16), block=256 (4 waves 32ci x 32px).
// ---------------------------------------------------------------------------
__global__ __launch_bounds__(256) void conv_t(
    const short* __restrict__ Ypb,   // [n][58][68][128] bf16 swz
    const short* __restrict__ Wt,    // [9][64][128] bf16 swz
    const float* __restrict__ x,     // fp32 NCHW
    short* __restrict__ Rp) {        // [n][58][68][64] bf16 swz
    __shared__ short ys[3 * 68 * 128];   // 52224 B; reused as transpose buf
    const int r = blockIdx.x + 1, n = blockIdx.y, tid = threadIdx.x;
    {
        const short8* src = (const short8*)(Ypb + ((size_t)(n * 58 + (r - 1)) * 68) * 128);
        short8* d = (short8*)ys;
        for (int j = tid; j < 26112 / 8; j += 256) d[j] = src[j];
    }
    __syncthreads();

    const int lane = tid & 63, wid = tid >> 6, qh = lane >> 5, l31 = lane & 31;
    const int cib = (wid & 1) * 32, vb = (wid >> 1) * 32;
    const int ci = cib + l31;
    const int v = vb + l31;
    int goffA[8], bg[3][8];
#pragma unroll
    for (int s = 0; s < 8; ++s) goffA[s] = 8 * ((2 * s + qh) ^ (ci & 7));
#pragma unroll
    for (int dw = 0; dw < 3; ++dw) {
        int key = (l31 + dw + 1) & 7;    // vb % 8 == 0
#pragma unroll
        for (int s = 0; s < 8; ++s) bg[dw][s] = 8 * ((2 * s + qh) ^ key);
    }
    const short* wbase = Wt + ci * 128;

    f32x16 acc;
#pragma unroll
    for (int i = 0; i < 16; ++i) acc[i] = 0.f;

    short8 Af[2][8];
#pragma unroll
    for (int s = 0; s < 8; ++s) Af[0][s] = *(const short8*)(wbase + goffA[s]);

#pragma unroll
    for (int t = 0; t < 9; ++t) {
        if (t + 1 < 9) {
#pragma unroll
            for (int s = 0; s < 8; ++s)
                Af[(t + 1) & 1][s] = *(const short8*)(wbase + (t + 1) * 8192 + goffA[s]);
        }
        const int dh = t / 3, dw = t % 3;
        const int b_base = (dh * 68 + (v + dw + 1)) * 128;
#pragma unroll
        for (int s = 0; s < 8; ++s) {
            short8 bv = *(const short8*)(ys + b_base + bg[dw][s]);
            acc = __builtin_amdgcn_mfma_f32_32x32x16_bf16(Af[t & 1][s], bv, acc, 0, 0, 0);
        }
    }

    // ---- epilogue: r = x - acc, write bf16 NHWC swizzled via LDS transpose
    __syncthreads();
    short* tb = ys;                       // [64][72]
    const int h = r - 1;
    const bool valid = v < 56;
    const size_t xbase = ((size_t)n * 64) * 3136 + (size_t)h * 56 + v;
#pragma unroll
    for (int reg = 0; reg < 16; ++reg) {
        const int cir = cib + (reg & 3) + 8 * (reg >> 2) + 4 * qh;
        float rv = 0.f;
        if (valid) rv = x[xbase + (size_t)cir * 3136] - acc[reg];
        tb[v * 72 + cir] = f2bf(rv);
    }
    __syncthreads();
    short* rdst = Rp + ((size_t)(n * 58 + r) * 68) * 64;
    for (int item = tid; item < 56 * 8; item += 256) {
        int vv = item >> 3, g = item & 7;
        short8 val = *(const short8*)(tb + vv * 72 + 8 * g);
        int s = vv + 2;
        *(short8*)(rdst + (s << 6) + 8 * (g ^ (s & 7))) = val;
    }
}

// ---------------------------------------------------------------------------
extern "C" void kernel_launch(void* const* d_in, const int* in_sizes, int n_in,
                              void* d_out, int out_size, void* d_ws, size_t ws_size,
                              hipStream_t stream) {
    const float* x = (const float*)d_in[0];   // [16,64,56,56] fp32
    const float* W = (const float*)d_in[1];   // [128,64,3,3]  fp32
    float* out = (float*)d_out;               // [16,128,56,56] fp32

    // ws layout: y_f32 | cp_f32 | Xp | Rp | Yp | Wf | Wt   (~84 MB)
    const size_t YN = 6422528;                 // 16*128*3136
    const size_t XPN = (size_t)16 * 58 * 68 * 64;   // 4,038,656
    const size_t YPN = (size_t)16 * 58 * 68 * 128;  // 8,077,312
    float* y  = (float*)d_ws;
    float* cp = y + YN;
    short* Xp = (short*)(cp + YN);
    short* Rp = Xp + XPN;
    short* Yp = Rp + XPN;
    short* Wf = Yp + YPN;
    short* Wt = Wf + 9 * 128 * 64;

    // zero Rp+Yp (contiguous span) so pad regions are 0 under re-poisoning
    const int n4 = (int)((XPN + YPN) * 2 / 16);   // 1,514,496 float4s
    hipLaunchKernelGGL(zero_kernel, dim3((n4 + 255) / 256), dim3(256), 0, stream,
                       (float4*)Rp, n4);
    hipLaunchKernelGGL(wnorm_pack, dim3(128), dim3(64), 0, stream, W, Wf, Wt);
    hipLaunchKernelGGL(pack_x, dim3(58, 16), dim3(256), 0, stream, x, Xp);

    dim3 g(56, 16), b(256, 1, 1);
    // it0: c = shrink(MU * conv(x)); y = cp = c
    hipLaunchKernelGGL(conv_fwd, g, b, 0, stream, Xp, Wf, y, cp, Yp,
                       (float*)nullptr, 0, 0.f);
    double t = 1.0;
    for (int it = 1; it <= 5; ++it) {
        hipLaunchKernelGGL(conv_t, g, b, 0, stream, Yp, Wt, x, Rp);
        double tn = (1.0 + sqrt(1.0 + 4.0 * t * t)) / 2.0;
        float beta = (float)((t - 1.0) / tn);
        hipLaunchKernelGGL(conv_fwd, g, b, 0, stream, Rp, Wf, y, cp, Yp,
                           (it == 5) ? out : (float*)nullptr, (it == 5) ? 2 : 1,
                           beta);
        t = tn;
    }
}

// Round 5
// 428.084 us; speedup vs baseline: 6.1433x; 1.0391x over previous
//
#include <hip/hip_runtime.h>
#include <hip/hip_bf16.h>
#include <math.h>

typedef __attribute__((ext_vector_type(8))) short short8;
typedef __attribute__((ext_vector_type(16))) float f32x16;

#define MU_  0.1f
#define THR_ 0.01f

static __device__ inline short f2bf(float f) {
    __hip_bfloat16 h = __float2bfloat16(f);
    return *reinterpret_cast<short*>(&h);
}
static __device__ inline float bf2f(unsigned short u) {
    unsigned int x = ((unsigned int)u) << 16;
    return __builtin_bit_cast(float, x);
}

// ---------------------------------------------------------------------------
__global__ __launch_bounds__(256) void zero_kernel(float4* p, int n4) {
    int i = blockIdx.x * 256 + threadIdx.x;
    if (i < n4) p[i] = make_float4(0.f, 0.f, 0.f, 0.f);
}

// ---------------------------------------------------------------------------
// Normalize W, emit swizzled bf16 GEMM layouts.
// Wf[t][co][ci ^ ((co&7)<<3)] = Wn[co][ci*9+t]
// Wt[t][ci][co ^ ((ci&7)<<3)] = Wn[co][ci*9+(8-t)]
// ---------------------------------------------------------------------------
__global__ __launch_bounds__(64) void wnorm_pack(
    const float* __restrict__ W, short* __restrict__ Wf, short* __restrict__ Wt) {
    int co = blockIdx.x, ci = threadIdx.x;
    const float* wp = W + (co * 64 + ci) * 9;
    float v[9]; float s = 0.f;
#pragma unroll
    for (int t = 0; t < 9; ++t) { v[t] = wp[t]; s += v[t] * v[t]; }
#pragma unroll
    for (int off = 32; off; off >>= 1) s += __shfl_xor(s, off, 64);
    float inv = 1.0f / sqrtf(s + 1e-12f);
#pragma unroll
    for (int t = 0; t < 9; ++t) {
        Wf[(t * 128 + co) * 64 + (ci ^ ((co & 7) << 3))] = f2bf(v[t] * inv);
        Wt[(t * 64 + ci) * 128 + (co ^ ((ci & 7) << 3))] = f2bf(v[8 - t] * inv);
    }
}

// ---------------------------------------------------------------------------
// Pack x (fp32 NCHW) -> Xp bf16 padded NHWC swizzled [n][58][68][64].
// ---------------------------------------------------------------------------
__global__ __launch_bounds__(256) void pack_x(
    const float* __restrict__ x, short* __restrict__ Xp) {
    __shared__ float lx[64 * 57];
    int row = blockIdx.x, n = blockIdx.y, tid = threadIdx.x;
    short* dst = Xp + ((size_t)(n * 58 + row) * 68) * 64;
    if (row >= 1 && row <= 56) {
        int h = row - 1;
        for (int j = tid; j < 64 * 56; j += 256) {
            int ci = j / 56, w = j - ci * 56;
            lx[ci * 57 + w] = x[((size_t)(n * 64 + ci)) * 3136 + h * 56 + w];
        }
        __syncthreads();
        for (int j = tid; j < 68 * 64; j += 256) {
            int s = j >> 6, ci = j & 63;
            float val = (s >= 2 && s < 58) ? lx[ci * 57 + (s - 2)] : 0.f;
            dst[(s << 6) + (ci ^ ((s & 7) << 3))] = f2bf(val);
        }
    } else {
        for (int j = tid; j < 68 * 64; j += 256) dst[j] = 0;
    }
}

// ---------------------------------------------------------------------------
// Forward conv 64->128 implicit GEMM + fused FISTA epilogue.
// grid=(56 rows, 2 co-halves, 16 n), block=256.
// Wave tile: 32co x 32px; wave = (co-sub = wid&1, px-half = wid>>1).
// mode 0: it0 (c=shrink(MU*acc); y=cp=c)
// mode 1: middle (c=shrink(y+MU*acc); y=c+beta*(c-cp); cp=c)
// mode 2: final  (out = shrink(y+MU*acc))
// ---------------------------------------------------------------------------
__global__ __launch_bounds__(256) void conv_fwd(
    const short* __restrict__ inp,   // [n][58][68][64] bf16 swz
    const short* __restrict__ Wf,    // [9][128][64] bf16 swz
    float* __restrict__ y,
    unsigned short* __restrict__ cpb,  // bf16-bits NCHW
    short* __restrict__ Yp,          // [n][58][68][128] bf16 swz
    float* __restrict__ outp, int mode, float beta) {
    __shared__ short xs[3 * 68 * 64];   // 26112 B; reused as transpose buf
    const int r = blockIdx.x + 1, cb = blockIdx.y, n = blockIdx.z, tid = threadIdx.x;
    {   // stage 3 contiguous input rows
        const short8* src = (const short8*)(inp + ((size_t)(n * 58 + (r - 1)) * 68) * 64);
        short8* d = (short8*)xs;
        for (int j = tid; j < 1632; j += 256) d[j] = src[j];
    }
    __syncthreads();

    const int lane = tid & 63, wid = tid >> 6, qh = lane >> 5, v0 = lane & 31;
    const int ms = wid & 1, ph = wid >> 1;
    const int co = cb * 64 + ms * 32 + v0;   // A-operand row
    const int v  = ph * 32 + v0;             // pixel within row
    const int h  = r - 1;
    const bool valid = v < 56;
    const size_t obase = ((size_t)(n * 128 + cb * 64 + ms * 32)) * 3136 +
                         (size_t)h * 56 + v;

    // --- prefetch epilogue operands (ride under the MFMA loop) ---
    float ypre[16]; unsigned short cpre[16];
    if (mode != 0 && valid) {
#pragma unroll
        for (int reg = 0; reg < 16; ++reg) {
            const int crl = (reg & 3) + 8 * (reg >> 2) + 4 * qh;   // 0..31
            ypre[reg] = y[obase + (size_t)crl * 3136];
            if (mode == 1) cpre[reg] = cpb[obase + (size_t)crl * 3136];
        }
    }

    int goffA[4], bg[3][4];
#pragma unroll
    for (int s = 0; s < 4; ++s) goffA[s] = 8 * ((2 * s + qh) ^ (v0 & 7));
#pragma unroll
    for (int dw = 0; dw < 3; ++dw) {
        int key = (v0 + dw + 1) & 7;
#pragma unroll
        for (int s = 0; s < 4; ++s) bg[dw][s] = 8 * ((2 * s + qh) ^ key);
    }
    const short* wbase = Wf + co * 64;

    f32x16 acc;
#pragma unroll
    for (int i = 0; i < 16; ++i) acc[i] = 0.f;

    short8 Af[2][4];
#pragma unroll
    for (int s = 0; s < 4; ++s) Af[0][s] = *(const short8*)(wbase + goffA[s]);

#pragma unroll
    for (int t = 0; t < 9; ++t) {
        if (t + 1 < 9) {
#pragma unroll
            for (int s = 0; s < 4; ++s)
                Af[(t + 1) & 1][s] = *(const short8*)(wbase + (t + 1) * 8192 + goffA[s]);
        }
        const int dh = t / 3, dw = t % 3;
        const int b_base = (dh * 68 + (v + dw + 1)) * 64;
#pragma unroll
        for (int s = 0; s < 4; ++s) {
            short8 bv = *(const short8*)(xs + b_base + bg[dw][s]);
            acc = __builtin_amdgcn_mfma_f32_32x32x16_bf16(Af[t & 1][s], bv, acc, 0, 0, 0);
        }
    }

    // ---- epilogue ----
    __syncthreads();          // xs dead -> transpose buffer [64 px][72 ch]
    short* tb = xs;
#pragma unroll
    for (int reg = 0; reg < 16; ++reg) {
        const int crl = (reg & 3) + 8 * (reg >> 2) + 4 * qh;   // 0..31
        const size_t o = obase + (size_t)crl * 3136;
        const float a = acc[reg];
        float ynew = 0.f;
        if (mode == 0) {
            float c = fmaxf(MU_ * a - THR_, 0.f);
            ynew = c;
            if (valid) { y[o] = c; cpb[o] = (unsigned short)f2bf(c); }
        } else if (mode == 1) {
            if (valid) {
                float c = fmaxf(ypre[reg] + MU_ * a - THR_, 0.f);
                ynew = c + beta * (c - bf2f(cpre[reg]));
                y[o] = ynew; cpb[o] = (unsigned short)f2bf(c);
            }
        } else {
            if (valid) {
                float c = fmaxf(ypre[reg] + MU_ * a - THR_, 0.f);
                outp[o] = c;
            }
        }
        if (mode != 2) tb[v * 72 + ms * 32 + crl] = f2bf(ynew);
    }
    if (mode != 2) {
        __syncthreads();
        short* ydst = Yp + ((size_t)(n * 58 + r) * 68) * 128;
        for (int item = tid; item < 56 * 8; item += 256) {
            int vv = item >> 3, g = item & 7;          // 8 groups = this half's 64 ch
            short8 val = *(const short8*)(tb + vv * 72 + 8 * g);
            int s = vv + 2;
            *(short8*)(ydst + s * 128 + 8 * ((g + 8 * cb) ^ (s & 7))) = val;
        }
    }
}

// ---------------------------------------------------------------------------
// Transpose conv 128->64 implicit GEMM with fused residual r = x - D^T y.
// grid=(56,16), block=256 (4 waves 32ci x 32px). x prefetched pre-loop.
// ---------------------------------------------------------------------------
__global__ __launch_bounds__(256) void conv_t(
    const short* __restrict__ Ypb,   // [n][58][68][128] bf16 swz
    const short* __restrict__ Wt,    // [9][64][128] bf16 swz
    const float* __restrict__ x,     // fp32 NCHW
    short* __restrict__ Rp) {        // [n][58][68][64] bf16 swz
    __shared__ short ys[3 * 68 * 128];   // 52224 B; reused as transpose buf
    const int r = blockIdx.x + 1, n = blockIdx.y, tid = threadIdx.x;
    {
        const short8* src = (const short8*)(Ypb + ((size_t)(n * 58 + (r - 1)) * 68) * 128);
        short8* d = (short8*)ys;
        for (int j = tid; j < 3264; j += 256) d[j] = src[j];
    }
    __syncthreads();

    const int lane = tid & 63, wid = tid >> 6, qh = lane >> 5, l31 = lane & 31;
    const int cib = (wid & 1) * 32, vb = (wid >> 1) * 32;
    const int ci = cib + l31;
    const int v = vb + l31;
    const int h = r - 1;
    const bool valid = v < 56;

    // --- prefetch residual base x (rides under MFMA loop) ---
    const size_t xbase = ((size_t)n * 64) * 3136 + (size_t)h * 56 + v;
    float xpre[16];
    if (valid) {
#pragma unroll
        for (int reg = 0; reg < 16; ++reg) {
            const int cir = cib + (reg & 3) + 8 * (reg >> 2) + 4 * qh;
            xpre[reg] = x[xbase + (size_t)cir * 3136];
        }
    }

    int goffA[8], bg[3][8];
#pragma unroll
    for (int s = 0; s < 8; ++s) goffA[s] = 8 * ((2 * s + qh) ^ (ci & 7));
#pragma unroll
    for (int dw = 0; dw < 3; ++dw) {
        int key = (l31 + dw + 1) & 7;    // vb % 8 == 0
#pragma unroll
        for (int s = 0; s < 8; ++s) bg[dw][s] = 8 * ((2 * s + qh) ^ key);
    }
    const short* wbase = Wt + ci * 128;

    f32x16 acc;
#pragma unroll
    for (int i = 0; i < 16; ++i) acc[i] = 0.f;

    short8 Af[2][8];
#pragma unroll
    for (int s = 0; s < 8; ++s) Af[0][s] = *(const short8*)(wbase + goffA[s]);

#pragma unroll
    for (int t = 0; t < 9; ++t) {
        if (t + 1 < 9) {
#pragma unroll
            for (int s = 0; s < 8; ++s)
                Af[(t + 1) & 1][s] = *(const short8*)(wbase + (t + 1) * 8192 + goffA[s]);
        }
        const int dh = t / 3, dw = t % 3;
        const int b_base = (dh * 68 + (v + dw + 1)) * 128;
#pragma unroll
        for (int s = 0; s < 8; ++s) {
            short8 bv = *(const short8*)(ys + b_base + bg[dw][s]);
            acc = __builtin_amdgcn_mfma_f32_32x32x16_bf16(Af[t & 1][s], bv, acc, 0, 0, 0);
        }
    }

    // ---- epilogue: r = x - acc -> bf16 NHWC swizzled via LDS transpose
    __syncthreads();
    short* tb = ys;                       // [64 px][72 ch]
#pragma unroll
    for (int reg = 0; reg < 16; ++reg) {
        const int cir = cib + (reg & 3) + 8 * (reg >> 2) + 4 * qh;
        float rv = 0.f;
        if (valid) rv = xpre[reg] - acc[reg];
        tb[v * 72 + cir] = f2bf(rv);
    }
    __syncthreads();
    short* rdst = Rp + ((size_t)(n * 58 + r) * 68) * 64;
    for (int item = tid; item < 56 * 8; item += 256) {
        int vv = item >> 3, g = item & 7;
        short8 val = *(const short8*)(tb + vv * 72 + 8 * g);
        int s = vv + 2;
        *(short8*)(rdst + (s << 6) + 8 * (g ^ (s & 7))) = val;
    }
}

// ---------------------------------------------------------------------------
extern "C" void kernel_launch(void* const* d_in, const int* in_sizes, int n_in,
                              void* d_out, int out_size, void* d_ws, size_t ws_size,
                              hipStream_t stream) {
    const float* x = (const float*)d_in[0];   // [16,64,56,56] fp32
    const float* W = (const float*)d_in[1];   // [128,64,3,3]  fp32
    float* out = (float*)d_out;               // [16,128,56,56] fp32

    // ws layout: y_f32 | cp_bf16 | Xp | Rp | Yp | Wf | Wt   (~71 MB)
    const size_t YN = 6422528;                      // 16*128*3136
    const size_t XPN = (size_t)16 * 58 * 68 * 64;   // 4,038,656
    const size_t YPN = (size_t)16 * 58 * 68 * 128;  // 8,077,312
    float* y  = (float*)d_ws;
    unsigned short* cpb = (unsigned short*)(y + YN);
    short* Xp = (short*)(cpb + YN);
    short* Rp = Xp + XPN;
    short* Yp = Rp + XPN;
    short* Wf = Yp + YPN;
    short* Wt = Wf + 9 * 128 * 64;

    // zero Rp+Yp (contiguous) so pad regions are 0 under ws re-poisoning
    const int n4 = (int)((XPN + YPN) * 2 / 16);
    hipLaunchKernelGGL(zero_kernel, dim3((n4 + 255) / 256), dim3(256), 0, stream,
                       (float4*)Rp, n4);
    hipLaunchKernelGGL(wnorm_pack, dim3(128), dim3(64), 0, stream, W, Wf, Wt);
    hipLaunchKernelGGL(pack_x, dim3(58, 16), dim3(256), 0, stream, x, Xp);

    dim3 gf(56, 2, 16), gt(56, 16), b(256, 1, 1);
    // it0: c = shrink(MU * conv(x)); y = cp = c
    hipLaunchKernelGGL(conv_fwd, gf, b, 0, stream, Xp, Wf, y, cpb, Yp,
                       (float*)nullptr, 0, 0.f);
    double t = 1.0;
    for (int it = 1; it <= 5; ++it) {
        hipLaunchKernelGGL(conv_t, gt, b, 0, stream, Yp, Wt, x, Rp);
        double tn = (1.0 + sqrt(1.0 + 4.0 * t * t)) / 2.0;
        float beta = (float)((t - 1.0) / tn);
        hipLaunchKernelGGL(conv_fwd, gf, b, 0, stream, Rp, Wf, y, cpb, Yp,
                           (it == 5) ? out : (float*)nullptr, (it == 5) ? 2 : 1,
                           beta);
        t = tn;
    }
}

// Round 6
// 406.059 us; speedup vs baseline: 6.4765x; 1.0542x over previous
//
#include <hip/hip_runtime.h>
#include <hip/hip_bf16.h>
#include <math.h>

typedef __attribute__((ext_vector_type(8))) short short8;
typedef __attribute__((ext_vector_type(16))) float f32x16;

#define MU_  0.1f
#define THR_ 0.01f

static __device__ inline short f2bf(float f) {
    __hip_bfloat16 h = __float2bfloat16(f);
    return *reinterpret_cast<short*>(&h);
}
static __device__ inline float bf2f(unsigned short u) {
    unsigned int x = ((unsigned int)u) << 16;
    return __builtin_bit_cast(float, x);
}

// ---------------------------------------------------------------------------
__global__ __launch_bounds__(256) void zero_kernel(float4* p, int n4) {
    int i = blockIdx.x * 256 + threadIdx.x;
    if (i < n4) p[i] = make_float4(0.f, 0.f, 0.f, 0.f);
}

// ---------------------------------------------------------------------------
// Normalize W, emit swizzled bf16 GEMM layouts.
// Wf[t][co][ci ^ ((co&7)<<3)] = Wn[co][ci*9+t]
// Wt[t][ci][co ^ ((ci&7)<<3)] = Wn[co][ci*9+(8-t)]
// ---------------------------------------------------------------------------
__global__ __launch_bounds__(64) void wnorm_pack(
    const float* __restrict__ W, short* __restrict__ Wf, short* __restrict__ Wt) {
    int co = blockIdx.x, ci = threadIdx.x;
    const float* wp = W + (co * 64 + ci) * 9;
    float v[9]; float s = 0.f;
#pragma unroll
    for (int t = 0; t < 9; ++t) { v[t] = wp[t]; s += v[t] * v[t]; }
#pragma unroll
    for (int off = 32; off; off >>= 1) s += __shfl_xor(s, off, 64);
    float inv = 1.0f / sqrtf(s + 1e-12f);
#pragma unroll
    for (int t = 0; t < 9; ++t) {
        Wf[(t * 128 + co) * 64 + (ci ^ ((co & 7) << 3))] = f2bf(v[t] * inv);
        Wt[(t * 64 + ci) * 128 + (co ^ ((ci & 7) << 3))] = f2bf(v[8 - t] * inv);
    }
}

// ---------------------------------------------------------------------------
// Pack x (fp32 NCHW) -> Xp bf16 padded NHWC swizzled [n][58][68][64].
// ---------------------------------------------------------------------------
__global__ __launch_bounds__(256) void pack_x(
    const float* __restrict__ x, short* __restrict__ Xp) {
    __shared__ float lx[64 * 57];
    int row = blockIdx.x, n = blockIdx.y, tid = threadIdx.x;
    short* dst = Xp + ((size_t)(n * 58 + row) * 68) * 64;
    if (row >= 1 && row <= 56) {
        int h = row - 1;
        for (int j = tid; j < 64 * 56; j += 256) {
            int ci = j / 56, w = j - ci * 56;
            lx[ci * 57 + w] = x[((size_t)(n * 64 + ci)) * 3136 + h * 56 + w];
        }
        __syncthreads();
        for (int j = tid; j < 68 * 64; j += 256) {
            int s = j >> 6, ci = j & 63;
            float val = (s >= 2 && s < 58) ? lx[ci * 57 + (s - 2)] : 0.f;
            dst[(s << 6) + (ci ^ ((s & 7) << 3))] = f2bf(val);
        }
    } else {
        for (int j = tid; j < 68 * 64; j += 256) dst[j] = 0;
    }
}

// ---------------------------------------------------------------------------
// Forward conv 64->128 implicit GEMM + fused FISTA epilogue; all FISTA state
// (y, c_prev) lives in bf16 swizzled padded NHWC (Yp, Cp).
// grid=(56 rows, 2 co-halves, 16 n), block=256; wave tile 32co x 32px.
// mode 0: c=shrink(MU*acc); y=cp=c
// mode 1: c=shrink(y_old+MU*acc); y=c+beta*(c-cp_old); cp=c
// mode 2: out=shrink(y_old+MU*acc)  (fp32 NCHW, no state writes)
// ---------------------------------------------------------------------------
__global__ __launch_bounds__(256) void conv_fwd(
    const short* __restrict__ inp,   // [n][58][68][64] bf16 swz (Xp or Rp)
    const short* __restrict__ Wf,    // [9][128][64] bf16 swz
    short* __restrict__ Yp,          // [n][58][68][128] bf16 swz (y state)
    short* __restrict__ Cp,          // [n][58][68][128] bf16 swz (c_prev)
    float* __restrict__ outp, int mode, float beta) {
    __shared__ short xs[3 * 68 * 64];   // 26112 B; reused post-MFMA
    const int r = blockIdx.x + 1, cb = blockIdx.y, n = blockIdx.z, tid = threadIdx.x;
    {   // stage 3 contiguous input rows
        const short8* src = (const short8*)(inp + ((size_t)(n * 58 + (r - 1)) * 68) * 64);
        short8* d = (short8*)xs;
        for (int j = tid; j < 1632; j += 256) d[j] = src[j];
    }

    // contiguous-domain prefetch of old y / c_prev (coalesced short8; rides
    // under staging + MFMA; bounced to C-layout via LDS after the loop)
    const size_t prow = ((size_t)(n * 58 + r) * 68) * 128;
    short8 yold8[2], cold8[2];
    int pvv[2], pg[2]; bool pok[2];
#pragma unroll
    for (int k = 0; k < 2; ++k) {
        int item = tid + k * 256;
        pok[k] = item < 448;
        pvv[k] = item >> 3; pg[k] = item & 7;
        if (mode != 0 && pok[k]) {
            int s = pvv[k] + 2;
            size_t off = prow + (size_t)s * 128 + 8 * ((pg[k] + 8 * cb) ^ (s & 7));
            yold8[k] = *(const short8*)(Yp + off);
            if (mode == 1) cold8[k] = *(const short8*)(Cp + off);
        }
    }
    __syncthreads();

    const int lane = tid & 63, wid = tid >> 6, qh = lane >> 5, v0 = lane & 31;
    const int ms = wid & 1, ph = wid >> 1;
    const int co = cb * 64 + ms * 32 + v0;   // A-operand row
    const int v  = ph * 32 + v0;             // pixel within row
    const int h  = r - 1;

    int goffA[4], bg[3][4];
#pragma unroll
    for (int s = 0; s < 4; ++s) goffA[s] = 8 * ((2 * s + qh) ^ (v0 & 7));
#pragma unroll
    for (int dw = 0; dw < 3; ++dw) {
        int key = (v0 + dw + 1) & 7;
#pragma unroll
        for (int s = 0; s < 4; ++s) bg[dw][s] = 8 * ((2 * s + qh) ^ key);
    }
    const short* wbase = Wf + co * 64;

    f32x16 acc;
#pragma unroll
    for (int i = 0; i < 16; ++i) acc[i] = 0.f;

    short8 Af[2][4];
#pragma unroll
    for (int s = 0; s < 4; ++s) Af[0][s] = *(const short8*)(wbase + goffA[s]);

#pragma unroll
    for (int t = 0; t < 9; ++t) {
        if (t + 1 < 9) {
#pragma unroll
            for (int s = 0; s < 4; ++s)
                Af[(t + 1) & 1][s] = *(const short8*)(wbase + (t + 1) * 8192 + goffA[s]);
        }
        const int dh = t / 3, dw = t % 3;
        const int b_base = (dh * 68 + (v + dw + 1)) * 64;
#pragma unroll
        for (int s = 0; s < 4; ++s) {
            short8 bv = *(const short8*)(xs + b_base + bg[dw][s]);
            acc = __builtin_amdgcn_mfma_f32_32x32x16_bf16(Af[t & 1][s], bv, acc, 0, 0, 0);
        }
    }

    // ---- epilogue ----
    __syncthreads();                 // xs dead
    short* tb_y = xs;                // [64 px][72 ch], XOR-swizzled by (v&3)
    short* tb_c = xs + 4608;
    if (mode != 0) {                 // dump prefetched old state to LDS
#pragma unroll
        for (int k = 0; k < 2; ++k) if (pok[k]) {
            int o = pvv[k] * 72 + 8 * (pg[k] ^ (pvv[k] & 3));
            *(short8*)(tb_y + o) = yold8[k];
            if (mode == 1) *(short8*)(tb_c + o) = cold8[k];
        }
    }
    __syncthreads();
    // per-lane C-layout math; in-place slot update (1:1 lane<->slot ownership)
#pragma unroll
    for (int reg = 0; reg < 16; ++reg) {
        const int crl = (reg & 3) + 8 * (reg >> 2) + 4 * qh;
        const int lch = ms * 32 + crl;
        const int slot = v * 72 + (lch ^ ((v & 3) << 3));
        const float a = acc[reg];
        if (mode == 0) {
            float c = fmaxf(MU_ * a - THR_, 0.f);
            short cb16 = f2bf(c);
            tb_y[slot] = cb16;
            tb_c[slot] = cb16;
        } else if (mode == 1) {
            float yold = bf2f((unsigned short)tb_y[slot]);
            float cold = bf2f((unsigned short)tb_c[slot]);
            float c = fmaxf(yold + MU_ * a - THR_, 0.f);
            float ynew = c + beta * (c - cold);
            tb_y[slot] = f2bf(ynew);
            tb_c[slot] = f2bf(c);
        } else {
            if (v < 56) {
                float yold = bf2f((unsigned short)tb_y[slot]);
                float c = fmaxf(yold + MU_ * a - THR_, 0.f);
                outp[((size_t)(n * 128 + cb * 64 + lch)) * 3136 + h * 56 + v] = c;
            }
        }
    }
    if (mode != 2) {                 // contiguous coalesced state writeback
        __syncthreads();
        short* ydst = Yp + prow;
        short* cdst = Cp + prow;
        for (int item = tid; item < 448; item += 256) {
            int vv = item >> 3, g = item & 7;
            int so = vv * 72 + 8 * (g ^ (vv & 3));
            short8 yv = *(const short8*)(tb_y + so);
            short8 cv = *(const short8*)(tb_c + so);
            int s = vv + 2;
            size_t off = (size_t)s * 128 + 8 * ((g + 8 * cb) ^ (s & 7));
            *(short8*)(ydst + off) = yv;
            *(short8*)(cdst + off) = cv;
        }
    }
}

// ---------------------------------------------------------------------------
// Transpose conv 128->64 implicit GEMM, fused residual r = x - D^T y with
// x read from bf16 Xp (same layout as Rp). grid=(56,16), block=256.
// ---------------------------------------------------------------------------
__global__ __launch_bounds__(256) void conv_t(
    const short* __restrict__ Ypb,   // [n][58][68][128] bf16 swz
    const short* __restrict__ Wt,    // [9][64][128] bf16 swz
    const short* __restrict__ Xp,    // [n][58][68][64] bf16 swz
    short* __restrict__ Rp) {        // [n][58][68][64] bf16 swz
    __shared__ short ys[3 * 68 * 128];   // 52224 B; reused post-MFMA
    const int r = blockIdx.x + 1, n = blockIdx.y, tid = threadIdx.x;
    {
        const short8* src = (const short8*)(Ypb + ((size_t)(n * 58 + (r - 1)) * 68) * 128);
        short8* d = (short8*)ys;
        for (int j = tid; j < 3264; j += 256) d[j] = src[j];
    }

    // contiguous-domain prefetch of x row (coalesced short8)
    const size_t prow = ((size_t)(n * 58 + r) * 68) * 64;
    short8 xold8[2];
    int pvv[2], pg[2]; bool pok[2];
#pragma unroll
    for (int k = 0; k < 2; ++k) {
        int item = tid + k * 256;
        pok[k] = item < 448;
        pvv[k] = item >> 3; pg[k] = item & 7;
        if (pok[k]) {
            int s = pvv[k] + 2;
            xold8[k] = *(const short8*)(Xp + prow + (size_t)s * 64 + 8 * (pg[k] ^ (s & 7)));
        }
    }
    __syncthreads();

    const int lane = tid & 63, wid = tid >> 6, qh = lane >> 5, l31 = lane & 31;
    const int cib = (wid & 1) * 32, vb = (wid >> 1) * 32;
    const int ci = cib + l31;
    const int v = vb + l31;

    int goffA[8], bg[3][8];
#pragma unroll
    for (int s = 0; s < 8; ++s) goffA[s] = 8 * ((2 * s + qh) ^ (ci & 7));
#pragma unroll
    for (int dw = 0; dw < 3; ++dw) {
        int key = (l31 + dw + 1) & 7;    // vb % 8 == 0
#pragma unroll
        for (int s = 0; s < 8; ++s) bg[dw][s] = 8 * ((2 * s + qh) ^ key);
    }
    const short* wbase = Wt + ci * 128;

    f32x16 acc;
#pragma unroll
    for (int i = 0; i < 16; ++i) acc[i] = 0.f;

    short8 Af[2][8];
#pragma unroll
    for (int s = 0; s < 8; ++s) Af[0][s] = *(const short8*)(wbase + goffA[s]);

#pragma unroll
    for (int t = 0; t < 9; ++t) {
        if (t + 1 < 9) {
#pragma unroll
            for (int s = 0; s < 8; ++s)
                Af[(t + 1) & 1][s] = *(const short8*)(wbase + (t + 1) * 8192 + goffA[s]);
        }
        const int dh = t / 3, dw = t % 3;
        const int b_base = (dh * 68 + (v + dw + 1)) * 128;
#pragma unroll
        for (int s = 0; s < 8; ++s) {
            short8 bv = *(const short8*)(ys + b_base + bg[dw][s]);
            acc = __builtin_amdgcn_mfma_f32_32x32x16_bf16(Af[t & 1][s], bv, acc, 0, 0, 0);
        }
    }

    // ---- epilogue: r = x - acc via LDS bounce, then coalesced writeback ----
    __syncthreads();                 // ys dead
    short* tb = ys;                  // [64 px][72 ch], XOR-swizzled by (v&3)
#pragma unroll
    for (int k = 0; k < 2; ++k) if (pok[k]) {
        *(short8*)(tb + pvv[k] * 72 + 8 * (pg[k] ^ (pvv[k] & 3))) = xold8[k];
    }
    __syncthreads();
#pragma unroll
    for (int reg = 0; reg < 16; ++reg) {
        const int cir = cib + (reg & 3) + 8 * (reg >> 2) + 4 * qh;
        const int slot = v * 72 + (cir ^ ((v & 3) << 3));
        float xo = bf2f((unsigned short)tb[slot]);
        tb[slot] = f2bf(xo - acc[reg]);
    }
    __syncthreads();
    short* rdst = Rp + prow;
    for (int item = tid; item < 448; item += 256) {
        int vv = item >> 3, g = item & 7;
        short8 val = *(const short8*)(tb + vv * 72 + 8 * (g ^ (vv & 3)));
        int s = vv + 2;
        *(short8*)(rdst + (size_t)s * 64 + 8 * (g ^ (s & 7))) = val;
    }
}

// ---------------------------------------------------------------------------
extern "C" void kernel_launch(void* const* d_in, const int* in_sizes, int n_in,
                              void* d_out, int out_size, void* d_ws, size_t ws_size,
                              hipStream_t stream) {
    const float* x = (const float*)d_in[0];   // [16,64,56,56] fp32
    const float* W = (const float*)d_in[1];   // [128,64,3,3]  fp32
    float* out = (float*)d_out;               // [16,128,56,56] fp32

    // ws layout (all bf16): Xp | Rp | Yp | Cp | Wf | Wt  (~49 MB)
    const size_t XPN = (size_t)16 * 58 * 68 * 64;   // 4,038,656
    const size_t YPN = 2 * XPN;                      // 8,077,312
    short* Xp = (short*)d_ws;
    short* Rp = Xp + XPN;
    short* Yp = Rp + XPN;
    short* Cp = Yp + YPN;
    short* Wf = Cp + YPN;
    short* Wt = Wf + 9 * 128 * 64;

    // zero Rp+Yp (contiguous) so pad regions are 0 under ws re-poisoning;
    // Cp pads are never read (mode-0 writes every interior cell mode-1 reads)
    const int n4 = (int)((XPN + YPN) * 2 / 16);
    hipLaunchKernelGGL(zero_kernel, dim3((n4 + 255) / 256), dim3(256), 0, stream,
                       (float4*)Rp, n4);
    hipLaunchKernelGGL(wnorm_pack, dim3(128), dim3(64), 0, stream, W, Wf, Wt);
    hipLaunchKernelGGL(pack_x, dim3(58, 16), dim3(256), 0, stream, x, Xp);

    dim3 gf(56, 2, 16), gt(56, 16), b(256, 1, 1);
    // it0: c = shrink(MU * conv(x)); y = cp = c
    hipLaunchKernelGGL(conv_fwd, gf, b, 0, stream, Xp, Wf, Yp, Cp,
                       (float*)nullptr, 0, 0.f);
    double t = 1.0;
    for (int it = 1; it <= 5; ++it) {
        hipLaunchKernelGGL(conv_t, gt, b, 0, stream, Yp, Wt, Xp, Rp);
        double tn = (1.0 + sqrt(1.0 + 4.0 * t * t)) / 2.0;
        float beta = (float)((t - 1.0) / tn);
        hipLaunchKernelGGL(conv_fwd, gf, b, 0, stream, Rp, Wf, Yp, Cp,
                           (it == 5) ? out : (float*)nullptr, (it == 5) ? 2 : 1,
                           beta);
        t = tn;
    }
}